// Round 1
// baseline (4497.909 us; speedup 1.0000x reference)
//
#include <hip/hip_runtime.h>
#include <hip/hip_bf16.h>
#include <cstddef>

#define NNODE  20000
#define NEDGE  240000
#define NGRAPH 200
#define DIN    118
#define HD     256
#define NBASIS 10
#define RHID   100
#define NLAYER 3
#define NSH    9
#define KTP    (NSH * HD)   // 2304

__device__ __forceinline__ float gelu_tanh(float v) {
  float v3 = v * v * v;
  return 0.5f * v * (1.f + tanhf(0.7978845608028654f * (v + 0.044715f * v3)));
}

// ---------------- edge geometry: sh[E,9], emb[E,10] ----------------
__global__ void edge_geom_kernel(const float* __restrict__ pos,
                                 const float* __restrict__ shift,
                                 const float* __restrict__ lat,
                                 const int* __restrict__ ei,
                                 const int* __restrict__ batch,
                                 float* __restrict__ sh,
                                 float* __restrict__ emb)
{
  int e = blockIdx.x * 256 + threadIdx.x;
  if (e >= NEDGE) return;
  int src = ei[e];
  int dst = ei[NEDGE + e];
  int b = batch[src];
  const float* L = lat + (size_t)b * 9;
  float s0 = shift[e * 3 + 0], s1 = shift[e * 3 + 1], s2 = shift[e * 3 + 2];
  float ev[3];
#pragma unroll
  for (int j = 0; j < 3; ++j)
    ev[j] = pos[dst * 3 + j] - pos[src * 3 + j] + s0 * L[j] + s1 * L[3 + j] + s2 * L[6 + j];
  float len = sqrtf(ev[0] * ev[0] + ev[1] * ev[1] + ev[2] * ev[2]);
  float inv = 1.f / (len + 1e-12f);
  float x = ev[0] * inv, y = ev[1] * inv, z = ev[2] * inv;
  const float c1 = 1.7320508075688772f;   // sqrt(3)
  const float c2 = 3.872983346207417f;    // sqrt(15)
  float* she = sh + (size_t)e * NSH;
  she[0] = 1.f;
  she[1] = c1 * x;
  she[2] = c1 * y;
  she[3] = c1 * z;
  she[4] = c2 * x * y;
  she[5] = c2 * y * z;
  she[6] = 1.1180339887498949f * (3.f * z * z - 1.f);  // sqrt(5)/2
  she[7] = c2 * x * z;
  she[8] = 1.9364916731037085f * (x * x - y * y);      // sqrt(15)/2
  const float step = 5.f / 11.f;
  const float sq = 3.1622776601683795f;   // sqrt(10)
  float* eme = emb + (size_t)e * NBASIS;
#pragma unroll
  for (int k = 0; k < NBASIS; ++k) {
    float d = (len - (float)(k + 1) * step) / step;
    eme[k] = (d > -1.f && d < 1.f) ? cosf(1.5707963267948966f * d) * sq : 0.f;
  }
}

// ---------------- CSR build ----------------
__global__ void deg_hist_kernel(const int* __restrict__ ei, int* __restrict__ deg)
{
  int e = blockIdx.x * 256 + threadIdx.x;
  if (e >= NEDGE) return;
  atomicAdd(&deg[ei[NEDGE + e]], 1);
}

__global__ void scan_kernel(const int* __restrict__ deg, int* __restrict__ rowptr)
{
  __shared__ int part[256];
  int t = threadIdx.x;
  const int chunk = (NNODE + 255) / 256;
  int start = t * chunk;
  int end = min(start + chunk, NNODE);
  int s = 0;
  for (int i = start; i < end; ++i) s += deg[i];
  part[t] = s;
  __syncthreads();
  for (int off = 1; off < 256; off <<= 1) {
    int v = (t >= off) ? part[t - off] : 0;
    __syncthreads();
    part[t] += v;
    __syncthreads();
  }
  int run = (t == 0) ? 0 : part[t - 1];
  for (int i = start; i < end; ++i) { rowptr[i] = run; run += deg[i]; }
  if (t == 255) rowptr[NNODE] = run;
}

__global__ void fill_kernel(const int* __restrict__ ei,
                            const int* __restrict__ rowptr,
                            int* __restrict__ cursor,
                            int* __restrict__ eids)
{
  int e = blockIdx.x * 256 + threadIdx.x;
  if (e >= NEDGE) return;
  int dst = ei[NEDGE + e];
  int p = atomicAdd(&cursor[dst], 1);
  eids[rowptr[dst] + p] = e;
}

// ---------------- Wcomb = inv_sqrt_deg * Wtp_flat[l] @ Wself[l] ----------------
__global__ void wcomb_kernel(const float* __restrict__ Wtp_l,
                             const float* __restrict__ Wself_l,
                             float* __restrict__ Wcomb)
{
  int p = blockIdx.x;       // 0..2303
  int j = threadIdx.x;      // 0..255
  const float* wrow = Wtp_l + (size_t)p * HD;
  float s = 0.f;
  for (int m = 0; m < HD; ++m) s += wrow[m] * Wself_l[m * HD + j];
  Wcomb[(size_t)p * HD + j] = s * 0.28867513459481287f;  // 1/sqrt(12)
}

// ---------------- gather: T[n, a*256+c] = sum_{e->n} sh[e,a]*h[src,c]*radial[e,c] ----------------
#define NPB 25
__global__ __launch_bounds__(256) void gather_T_kernel(
    const int* __restrict__ rowptr, const int* __restrict__ eids,
    const int* __restrict__ ei, const float* __restrict__ sh,
    const float* __restrict__ emb, const float* __restrict__ h,
    const float* __restrict__ r1l, const float* __restrict__ b1l,
    const float* __restrict__ r2l, float* __restrict__ T)
{
  int c = threadIdx.x;  // channel 0..255
  // cache r2 column c in registers
  float r2c[RHID];
#pragma unroll
  for (int k = 0; k < RHID; ++k) r2c[k] = r2l[k * HD + c];

  __shared__ float emb_s[2][NBASIS];
  __shared__ float sh_s[2][NSH];
  __shared__ float rh_s[2][RHID];

  int n0 = blockIdx.x * NPB;
  for (int n = n0; n < n0 + NPB; ++n) {
    int beg = rowptr[n], end = rowptr[n + 1];
    float acc[NSH];
#pragma unroll
    for (int a = 0; a < NSH; ++a) acc[a] = 0.f;
    int buf = 0;
    for (int j = beg; j < end; ++j, buf ^= 1) {
      int e = eids[j];
      int src = ei[e];
      if (c < NBASIS) emb_s[buf][c] = emb[(size_t)e * NBASIS + c];
      else if (c < NBASIS + NSH) sh_s[buf][c - NBASIS] = sh[(size_t)e * NSH + (c - NBASIS)];
      __syncthreads();
      if (c < RHID) {
        float hs = b1l[c];
#pragma unroll
        for (int k = 0; k < NBASIS; ++k) hs += emb_s[buf][k] * r1l[k * RHID + c];
        rh_s[buf][c] = hs / (1.f + expf(-hs));  // silu
      }
      __syncthreads();
      float radial = 0.f;
#pragma unroll
      for (int k = 0; k < RHID; ++k) radial += rh_s[buf][k] * r2c[k];
      float hv = h[(size_t)src * HD + c] * radial;
#pragma unroll
      for (int a = 0; a < NSH; ++a) acc[a] += sh_s[buf][a] * hv;
    }
    float* Tn = T + (size_t)n * KTP + c;
#pragma unroll
    for (int a = 0; a < NSH; ++a) Tn[a * HD] = acc[a];
  }
}

// ---------------- fused GEMM: C = act(A1@B1 + A2@B2), N fixed = 256 ----------------
#define BM 64
#define BN 64
#define BK 16
__global__ __launch_bounds__(256) void gemm_fused_kernel(
    const float* __restrict__ A1, const float* __restrict__ B1, int K1,
    const float* __restrict__ A2, const float* __restrict__ B2, int K2,
    float* __restrict__ C, int M, int act)
{
  __shared__ float As[BK][BM];
  __shared__ float Bs[BK][BN];
  int tid = threadIdx.x;
  int tx = tid & 15, ty = tid >> 4;
  int row0 = blockIdx.x * BM;
  int col0 = blockIdx.y * BN;
  float acc[4][4];
#pragma unroll
  for (int i = 0; i < 4; ++i)
#pragma unroll
    for (int j = 0; j < 4; ++j) acc[i][j] = 0.f;

  for (int pass = 0; pass < 2; ++pass) {
    const float* A = pass ? A2 : A1;
    const float* B = pass ? B2 : B1;
    int K = pass ? K2 : K1;
    if (A == nullptr || K <= 0) continue;
    for (int k0 = 0; k0 < K; k0 += BK) {
      {
        int r = tid >> 2;
        int kq = (tid & 3) * 4;
        int gr = row0 + r;
#pragma unroll
        for (int j = 0; j < 4; ++j) {
          int gk = k0 + kq + j;
          As[kq + j][r] = (gr < M && gk < K) ? A[(size_t)gr * K + gk] : 0.f;
        }
      }
      {
#pragma unroll
        for (int t = 0; t < 4; ++t) {
          int idx = tid + t * 256;
          int kk = idx >> 6, nn = idx & 63;
          int gk = k0 + kk;
          Bs[kk][nn] = (gk < K) ? B[(size_t)gk * HD + col0 + nn] : 0.f;
        }
      }
      __syncthreads();
#pragma unroll
      for (int kk = 0; kk < BK; ++kk) {
        float a[4], b[4];
#pragma unroll
        for (int i = 0; i < 4; ++i) a[i] = As[kk][ty * 4 + i];
#pragma unroll
        for (int j = 0; j < 4; ++j) b[j] = Bs[kk][tx * 4 + j];
#pragma unroll
        for (int i = 0; i < 4; ++i)
#pragma unroll
          for (int j = 0; j < 4; ++j) acc[i][j] += a[i] * b[j];
      }
      __syncthreads();
    }
  }
#pragma unroll
  for (int i = 0; i < 4; ++i) {
    int row = row0 + ty * 4 + i;
    if (row >= M) continue;
#pragma unroll
    for (int j = 0; j < 4; ++j) {
      float v = acc[i][j];
      if (act == 1) v = gelu_tanh(v);
      C[(size_t)row * HD + col0 + tx * 4 + j] = v;
    }
  }
}

// ---------------- node_out + graph sums ----------------
__global__ void node_out_kernel(const float* __restrict__ h,
                                const float* __restrict__ Wout,
                                const int* __restrict__ batch,
                                float* __restrict__ sums,
                                float* __restrict__ cnts)
{
  int n = blockIdx.x * 4 + (threadIdx.x >> 6);
  int lane = threadIdx.x & 63;
  if (n >= NNODE) return;
  float s = 0.f;
#pragma unroll
  for (int t = 0; t < 4; ++t) {
    int c = lane + t * 64;
    s += h[(size_t)n * HD + c] * Wout[c];
  }
#pragma unroll
  for (int off = 32; off > 0; off >>= 1) s += __shfl_down(s, off);
  if (lane == 0) {
    int g = batch[n];
    atomicAdd(&sums[g], s);
    atomicAdd(&cnts[g], 1.f);
  }
}

__global__ void finalize_kernel(const float* __restrict__ sums,
                                const float* __restrict__ cnts,
                                float* __restrict__ out)
{
  int g = threadIdx.x;
  if (g < NGRAPH) out[g] = sums[g] / fmaxf(cnts[g], 1.f);
}

// ---------------- host launch ----------------
extern "C" void kernel_launch(void* const* d_in, const int* in_sizes, int n_in,
                              void* d_out, int out_size, void* d_ws, size_t ws_size,
                              hipStream_t stream)
{
  (void)in_sizes; (void)n_in; (void)out_size;
  const float* x     = (const float*)d_in[0];
  const float* pos   = (const float*)d_in[1];
  const float* shift = (const float*)d_in[2];
  const float* lat   = (const float*)d_in[3];
  const float* Wemb  = (const float*)d_in[4];
  const float* r1    = (const float*)d_in[5];
  const float* b1    = (const float*)d_in[6];
  const float* r2    = (const float*)d_in[7];
  const float* Wtp   = (const float*)d_in[8];
  const float* Wself = (const float*)d_in[9];
  const float* Wskip = (const float*)d_in[10];
  const float* Wout  = (const float*)d_in[11];
  const int*   eidx  = (const int*)d_in[12];
  const int*   batch = (const int*)d_in[13];
  float* out = (float*)d_out;

  char* ws = (char*)d_ws;
  size_t off = 0;
  auto alloc = [&](size_t bytes) -> char* {
    char* p = ws + off;
    off += (bytes + 255) & ~(size_t)255;
    return p;
  };
  float* sh    = (float*)alloc((size_t)NEDGE * NSH * 4);
  float* emb   = (float*)alloc((size_t)NEDGE * NBASIS * 4);
  float* hA    = (float*)alloc((size_t)NNODE * HD * 4);
  float* hB    = (float*)alloc((size_t)NNODE * HD * 4);
  float* T     = (float*)alloc((size_t)NNODE * KTP * 4);
  float* Wcomb = (float*)alloc((size_t)KTP * HD * 4);
  int*   rowptr = (int*)alloc((size_t)(NNODE + 1) * 4);
  int*   deg    = (int*)alloc((size_t)NNODE * 4);
  int*   cursor = (int*)alloc((size_t)NNODE * 4);
  int*   eids   = (int*)alloc((size_t)NEDGE * 4);
  float* sums   = (float*)alloc((size_t)NGRAPH * 4);
  float* cnts   = (float*)alloc((size_t)NGRAPH * 4);
  if (off > ws_size) return;  // workspace too small (constant per process)

  // zero-init the buffers we accumulate into (ws is poisoned each call)
  hipMemsetAsync(deg, 0, (size_t)NNODE * 4, stream);
  hipMemsetAsync(cursor, 0, (size_t)NNODE * 4, stream);
  hipMemsetAsync(sums, 0, (size_t)NGRAPH * 4, stream);
  hipMemsetAsync(cnts, 0, (size_t)NGRAPH * 4, stream);

  const int EB = (NEDGE + 255) / 256;
  edge_geom_kernel<<<EB, 256, 0, stream>>>(pos, shift, lat, eidx, batch, sh, emb);
  deg_hist_kernel<<<EB, 256, 0, stream>>>(eidx, deg);
  scan_kernel<<<1, 256, 0, stream>>>(deg, rowptr);
  fill_kernel<<<EB, 256, 0, stream>>>(eidx, rowptr, cursor, eids);

  // h = x @ W_embed
  dim3 ggrid((NNODE + BM - 1) / BM, HD / BN);
  gemm_fused_kernel<<<ggrid, 256, 0, stream>>>(x, Wemb, DIN, nullptr, nullptr, 0,
                                               hA, NNODE, 0);

  float* hcur = hA;
  float* hnxt = hB;
  for (int l = 0; l < NLAYER; ++l) {
    const float* r1l = r1 + (size_t)l * NBASIS * RHID;
    const float* b1l = b1 + (size_t)l * RHID;
    const float* r2l = r2 + (size_t)l * RHID * HD;
    const float* Wtp_l = Wtp + (size_t)l * NSH * HD * HD;
    const float* Wself_l = Wself + (size_t)l * HD * HD;
    const float* Wskip_l = Wskip + (size_t)l * HD * HD;

    wcomb_kernel<<<KTP, 256, 0, stream>>>(Wtp_l, Wself_l, Wcomb);
    gather_T_kernel<<<NNODE / NPB, 256, 0, stream>>>(rowptr, eids, eidx, sh, emb,
                                                     hcur, r1l, b1l, r2l, T);
    gemm_fused_kernel<<<ggrid, 256, 0, stream>>>(T, Wcomb, KTP, hcur, Wskip_l, HD,
                                                 hnxt, NNODE, 1);
    float* tmp = hcur; hcur = hnxt; hnxt = tmp;
  }

  node_out_kernel<<<NNODE / 4, 256, 0, stream>>>(hcur, Wout, batch, sums, cnts);
  finalize_kernel<<<1, 256, 0, stream>>>(sums, cnts, out);
}